// Round 1
// 938.252 us; speedup vs baseline: 1.2427x; 1.2427x over previous
//
#include <hip/hip_runtime.h>
#include <stdint.h>

#define B 4
#define C 192
#define CA 96
#define HWN 65536
#define W2 128
#define HW2 16384
#define HEADS 8
#define CH 24
#define CAH 12

typedef short bf16x8 __attribute__((ext_vector_type(8)));
typedef short short4v __attribute__((ext_vector_type(4)));
typedef float f32x4 __attribute__((ext_vector_type(4)));
typedef unsigned int uint;

__device__ __forceinline__ float bf2f(short s) {
    union { uint u; float f; } v; v.u = ((uint)(unsigned short)s) << 16; return v.f;
}
__device__ __forceinline__ short f2bf(float f) {
    union { float f; uint u; } v; v.f = f;
    uint r = v.u + 0x7FFFu + ((v.u >> 16) & 1);
    return (short)(r >> 16);
}

// ---------------- K0: pack weights to bf16 ----------------
__global__ __launch_bounds__(256) void k_pack(const float* wk, const float* wv, const float* wapw,
                                              short* wk_t, short* wv_b, short* wapw_b) {
    int i = blockIdx.x * 256 + threadIdx.x;
    if (i < 331776) {                       // wk [co][ci][9] -> wk_t [tap][co][ci]
        int tap = i / 36864, r = i % 36864;
        int co = r / C, ci = r % C;
        wk_t[i] = f2bf(wk[(co * C + ci) * 9 + tap]);
    } else if (i < 331776 + 36864) {
        int j = i - 331776;
        wv_b[j] = f2bf(wv[j]);
    } else if (i < 331776 + 36864 + 18432) {
        int j = i - 368640;
        wapw_b[j] = f2bf(wapw[j]);
    }
}

// ---------------- K1: x [b][c][n] f32 -> xT [b][n][c] bf16 ----------------
__global__ __launch_bounds__(256) void k_transpose(const float* x, short* xT) {
    int bid = blockIdx.x;
    int b = bid >> 10;
    int n0 = (bid & 1023) << 6;
    __shared__ float tile[64][193];
    const float* xb = x + (size_t)b * C * HWN;
    int t = threadIdx.x;
    for (int it = 0; it < 12; ++it) {
        int i = t + it * 256;          // 0..3071
        int c = i >> 4;
        int j = i & 15;
        float4 v = *(const float4*)(xb + (size_t)c * HWN + n0 + j * 4);
        tile[j * 4 + 0][c] = v.x;
        tile[j * 4 + 1][c] = v.y;
        tile[j * 4 + 2][c] = v.z;
        tile[j * 4 + 3][c] = v.w;
    }
    __syncthreads();
    short* out = xT + ((size_t)b * HWN + n0) * C;
    for (int it = 0; it < 6; ++it) {
        int u = t + it * 256;          // 0..1535
        int n = u / 24;
        int cp = u % 24;
        int c0 = cp * 8;
        bf16x8 vv;
#pragma unroll
        for (int k2 = 0; k2 < 8; ++k2) vv[k2] = f2bf(tile[n][c0 + k2]);
        *(bf16x8*)(out + (size_t)n * C + c0) = vv;
    }
}

// ---------------- K2: k = conv3x3 s2 (192->192) via 9-tap implicit MFMA GEMM ----------------
__global__ __launch_bounds__(256) void k_kconv(const short* xT, const short* wk_t, short* kout) {
    int bid = blockIdx.x;
    int b = bid >> 8;
    int rem = bid & 255;
    int oh = rem >> 1;
    int owt = rem & 1;
    int tid = threadIdx.x;
    int lane = tid & 63;
    int wid = tid >> 6;
    int wm = wid & 1;          // co half (96)
    int wn = wid >> 1;         // px half (32)
    int l15 = lane & 15;
    int q = lane >> 4;

    f32x4 acc[6][2] = {};
    const short* xTb = xT + (size_t)b * HWN * C;
    int ow_base = owt * 64 + wn * 32;

    for (int tap = 0; tap < 9; ++tap) {
        int kh = tap / 3, kw = tap % 3;
        int ih = 2 * oh - 1 + kh;
        bool vrow = (unsigned)ih < 256u;
        int ihc = min(max(ih, 0), 255);
        const short* bp[2];
        bool bv[2];
#pragma unroll
        for (int nt = 0; nt < 2; ++nt) {
            int ow = ow_base + nt * 16 + l15;
            int iw = 2 * ow - 1 + kw;
            bv[nt] = vrow && ((unsigned)iw < 256u);
            int iwc = min(max(iw, 0), 255);
            bp[nt] = xTb + ((size_t)ihc * 256 + iwc) * C + q * 8;
        }
        const short* ap = wk_t + ((size_t)tap * C + (wm * 96 + l15)) * C + q * 8;
#pragma unroll
        for (int ks = 0; ks < 6; ++ks) {
            bf16x8 zf = {};
            bf16x8 bf[2];
#pragma unroll
            for (int nt = 0; nt < 2; ++nt) {
                bf16x8 raw = *(const bf16x8*)(bp[nt] + ks * 32);
                bf[nt] = bv[nt] ? raw : zf;
            }
#pragma unroll
            for (int mt = 0; mt < 6; ++mt) {
                bf16x8 af = *(const bf16x8*)(ap + (size_t)mt * 16 * C + ks * 32);
#pragma unroll
                for (int nt = 0; nt < 2; ++nt)
                    acc[mt][nt] = __builtin_amdgcn_mfma_f32_16x16x32_bf16(af, bf[nt], acc[mt][nt], 0, 0, 0);
            }
        }
    }
    __shared__ short lt[C][72];
#pragma unroll
    for (int mt = 0; mt < 6; ++mt)
#pragma unroll
        for (int nt = 0; nt < 2; ++nt) {
            int px = wn * 32 + nt * 16 + l15;
#pragma unroll
            for (int r = 0; r < 4; ++r) {
                int co = wm * 96 + mt * 16 + q * 4 + r;
                lt[co][px] = f2bf(acc[mt][nt][r]);
            }
        }
    __syncthreads();
    short* kb = kout + (size_t)b * C * HW2 + oh * W2 + owt * 64;
    for (int it = 0; it < 6; ++it) {
        int u = tid + it * 256;      // 0..1535 = 192*8
        int co = u >> 3;
        int ch = u & 7;
        bf16x8 vv = *(const bf16x8*)(&lt[co][ch * 8]);
        *(bf16x8*)(kb + (size_t)co * HW2 + ch * 8) = vv;
    }
}

// ---------------- K2b: depthwise q (3x3 s2) + a_dw (3x3 s2) from planar f32 x ----------------
// block = (b, oh, 16-channel group); thread = (channel, 8-wide ow group).
// 5x float4 loads per input row per thread (aligned chunks over the 17-wide window).
__global__ __launch_bounds__(256) void k_dw(const float* x, const float* wq, const float* wadw,
                                            short* qout, short* adwT) {
    int bid = blockIdx.x;
    int oh = bid & 127;
    int r2 = bid >> 7;              // b*12 + cg
    int cg = r2 % 12;
    int b  = r2 / 12;
    int t = threadIdx.x;
    int og = t & 15;                // ow group: ow0 = og*8
    int cl = t >> 4;                // 0..15 local channel
    int c = cg * 16 + cl;
    int ow0 = og * 8;

    float wq_r[9], wa_r[9];
#pragma unroll
    for (int k9 = 0; k9 < 9; ++k9) { wq_r[k9] = wq[c * 9 + k9]; wa_r[k9] = wadw[c * 9 + k9]; }

    const float* xp = x + (size_t)(b * C + c) * HWN;
    float qa[8] = {}, aa[8] = {};
    int ibase = 2 * ow0 - 4;
#pragma unroll
    for (int kh = 0; kh < 3; ++kh) {
        int ih = 2 * oh - 1 + kh;
        if ((unsigned)ih >= 256u) continue;     // zero pad (only oh==0, kh==0)
        const float* rp = xp + (size_t)ih * 256;
        float arr[20];
#pragma unroll
        for (int ck = 0; ck < 5; ++ck) {
            int iw = ibase + ck * 4;
            if (iw >= 0) {
                float4 v = *(const float4*)(rp + iw);
                arr[ck * 4 + 0] = v.x; arr[ck * 4 + 1] = v.y;
                arr[ck * 4 + 2] = v.z; arr[ck * 4 + 3] = v.w;
            } else {                             // left zero pad (og==0, chunk 0)
                arr[ck * 4 + 0] = 0.f; arr[ck * 4 + 1] = 0.f;
                arr[ck * 4 + 2] = 0.f; arr[ck * 4 + 3] = 0.f;
            }
        }
        float q0 = wq_r[kh * 3 + 0], q1 = wq_r[kh * 3 + 1], q2 = wq_r[kh * 3 + 2];
        float a0 = wa_r[kh * 3 + 0], a1 = wa_r[kh * 3 + 1], a2 = wa_r[kh * 3 + 2];
#pragma unroll
        for (int oz = 0; oz < 8; ++oz) {
            // ow = ow0+oz, iw = 2*ow-1+kw -> arr index 2*oz+3+kw
            float s0 = arr[2 * oz + 3], s1 = arr[2 * oz + 4], s2 = arr[2 * oz + 5];
            qa[oz] += q0 * s0 + q1 * s1 + q2 * s2;
            aa[oz] += a0 * s0 + a1 * s1 + a2 * s2;
        }
    }

    // q out: [b][c][n2], one coalesced 16B store per thread
    bf16x8 qv;
#pragma unroll
    for (int oz = 0; oz < 8; ++oz) qv[oz] = f2bf(qa[oz]);
    *(bf16x8*)(qout + (size_t)(b * C + c) * HW2 + oh * W2 + ow0) = qv;

    // adw out: [b][n2][c] — stage tile [128 ow][16 c] (pad 17) then 16B stores
    __shared__ short la[128][17];
#pragma unroll
    for (int oz = 0; oz < 8; ++oz) la[ow0 + oz][cl] = f2bf(aa[oz]);
    __syncthreads();
    {
        int ow = t >> 1;
        int jh = (t & 1) * 8;
        bf16x8 vv;
#pragma unroll
        for (int j = 0; j < 8; ++j) vv[j] = la[ow][jh + j];
        short* dst = adwT + ((size_t)b * HW2 + (size_t)oh * W2 + ow) * C + cg * 16 + jh;
        *(bf16x8*)dst = vv;
    }
}

// ---------------- K2c: a = pointwise(adwT) + bias, MFMA ----------------
__global__ __launch_bounds__(256) void k_apw(const short* adwT, const short* wapw_b, const float* bapw,
                                             short* aout) {
    int bid = blockIdx.x;
    int b = bid >> 7;
    int op0 = (bid & 127) << 7;
    int tid = threadIdx.x;
    int lane = tid & 63;
    int wid = tid >> 6;
    int wm = wid & 1, wn = wid >> 1;
    int l15 = lane & 15, q = lane >> 4;
    f32x4 acc[3][4] = {};
    const short* bb = adwT + ((size_t)b * HW2 + op0 + wn * 64 + l15) * C + q * 8;
    const short* ab0 = wapw_b + (size_t)(wm * 48 + l15) * C + q * 8;
#pragma unroll
    for (int ks = 0; ks < 6; ++ks) {
        bf16x8 bf[4];
#pragma unroll
        for (int nt = 0; nt < 4; ++nt)
            bf[nt] = *(const bf16x8*)(bb + (size_t)nt * 16 * C + ks * 32);
#pragma unroll
        for (int mt = 0; mt < 3; ++mt) {
            bf16x8 af = *(const bf16x8*)(ab0 + (size_t)mt * 16 * C + ks * 32);
#pragma unroll
            for (int nt = 0; nt < 4; ++nt)
                acc[mt][nt] = __builtin_amdgcn_mfma_f32_16x16x32_bf16(af, bf[nt], acc[mt][nt], 0, 0, 0);
        }
    }
    __shared__ short la[CA][136];
#pragma unroll
    for (int mt = 0; mt < 3; ++mt)
#pragma unroll
        for (int nt = 0; nt < 4; ++nt) {
            int px = wn * 64 + nt * 16 + l15;
#pragma unroll
            for (int r = 0; r < 4; ++r) {
                int d = wm * 48 + mt * 16 + q * 4 + r;
                la[d][px] = f2bf(acc[mt][nt][r] + bapw[d]);
            }
        }
    __syncthreads();
    short* abp = aout + (size_t)b * CA * HW2 + op0;
    for (int it = 0; it < 6; ++it) {
        int u = tid + it * 256;       // 0..1535 = 96*16
        int d = u >> 4;
        int ch = u & 15;
        bf16x8 vv = *(const bf16x8*)(&la[d][ch * 8]);
        *(bf16x8*)(abp + (size_t)d * HW2 + ch * 8) = vv;
    }
}

// ---------------- K4: raw attention dots (MFMA over n) + sum-of-squares, atomic partials ----------------
__global__ __launch_bounds__(64) void k_attn(const short* qb, const short* kb, const short* abuf,
                                             float* attn_a, float* attn_k,
                                             float* ssq, float* ssk, float* ssa) {
    int bid = blockIdx.x;
    int b = bid >> 9;
    int rem = bid & 511;
    int h = rem >> 6;
    int cid = rem & 63;
    int lane = threadIdx.x;
    int l15 = lane & 15, q = lane >> 4;
    int n_base = cid * 256 + q * 8;
    int c1 = min(16 + l15, 23);
    int da = min(l15, 11);
    const short* qrow0 = qb + ((size_t)(b * C + h * CH + l15)) * HW2 + n_base;
    const short* qrow1 = qb + ((size_t)(b * C + h * CH + c1)) * HW2 + n_base;
    const short* krow0 = kb + ((size_t)(b * C + h * CH + l15)) * HW2 + n_base;
    const short* krow1 = kb + ((size_t)(b * C + h * CH + c1)) * HW2 + n_base;
    const short* arow = abuf + ((size_t)(b * CA + h * CAH + da)) * HW2 + n_base;
    f32x4 aa[2] = {};
    f32x4 ak[2] = {};
    float sq0 = 0, sq1 = 0, sk0 = 0, sk1 = 0, sa0 = 0;
#pragma unroll
    for (int ks = 0; ks < 8; ++ks) {
        bf16x8 qf0 = *(const bf16x8*)(qrow0 + ks * 32);
        bf16x8 qf1 = *(const bf16x8*)(qrow1 + ks * 32);
        bf16x8 kf0 = *(const bf16x8*)(krow0 + ks * 32);
        bf16x8 kf1 = *(const bf16x8*)(krow1 + ks * 32);
        bf16x8 af = *(const bf16x8*)(arow + ks * 32);
        aa[0] = __builtin_amdgcn_mfma_f32_16x16x32_bf16(qf0, af, aa[0], 0, 0, 0);
        aa[1] = __builtin_amdgcn_mfma_f32_16x16x32_bf16(qf1, af, aa[1], 0, 0, 0);
        ak[0] = __builtin_amdgcn_mfma_f32_16x16x32_bf16(af, kf0, ak[0], 0, 0, 0);
        ak[1] = __builtin_amdgcn_mfma_f32_16x16x32_bf16(af, kf1, ak[1], 0, 0, 0);
#pragma unroll
        for (int j = 0; j < 8; ++j) {
            float f;
            f = bf2f(qf0[j]); sq0 += f * f;
            f = bf2f(qf1[j]); sq1 += f * f;
            f = bf2f(kf0[j]); sk0 += f * f;
            f = bf2f(kf1[j]); sk1 += f * f;
            f = bf2f(af[j]);  sa0 += f * f;
        }
    }
    sq0 += __shfl_xor(sq0, 16); sq0 += __shfl_xor(sq0, 32);
    sq1 += __shfl_xor(sq1, 16); sq1 += __shfl_xor(sq1, 32);
    sk0 += __shfl_xor(sk0, 16); sk0 += __shfl_xor(sk0, 32);
    sk1 += __shfl_xor(sk1, 16); sk1 += __shfl_xor(sk1, 32);
    sa0 += __shfl_xor(sa0, 16); sa0 += __shfl_xor(sa0, 32);
    if (lane < 16) atomicAdd(&ssq[b * C + h * CH + lane], sq0);
    if (lane < 8)  atomicAdd(&ssq[b * C + h * CH + 16 + lane], sq1);
    if (lane < 16) atomicAdd(&ssk[b * C + h * CH + lane], sk0);
    if (lane < 8)  atomicAdd(&ssk[b * C + h * CH + 16 + lane], sk1);
    if (lane < 12) atomicAdd(&ssa[b * CA + h * CAH + lane], sa0);

    float* pa = attn_a + (size_t)(b * HEADS + h) * CH * CAH;
#pragma unroll
    for (int mt = 0; mt < 2; ++mt)
#pragma unroll
        for (int r = 0; r < 4; ++r) {
            int cc = mt * 16 + q * 4 + r;
            if (cc < 24 && l15 < 12) atomicAdd(&pa[cc * CAH + l15], aa[mt][r]);
        }
    float* pk = attn_k + (size_t)(b * HEADS + h) * CAH * CH;
#pragma unroll
    for (int nt = 0; nt < 2; ++nt)
#pragma unroll
        for (int r = 0; r < 4; ++r) {
            int dd = q * 4 + r;
            int cc = nt * 16 + l15;
            if (dd < 12 && cc < 24) atomicAdd(&pk[dd * CH + cc], ak[nt][r]);
        }
}

// ---------------- K5a: scales + softmax + W = P@M ----------------
__global__ __launch_bounds__(256) void k_soft(const float* ssq, const float* ssk, const float* ssa,
                                              const float* attn_a, const float* attn_k,
                                              const float* temp_a, const float* temp_v, float* Wout) {
    int b = blockIdx.x;
    int t = threadIdx.x;
    __shared__ float sq[C], sk[C], sa[CA];
    __shared__ float P[HEADS * CH * CAH];
    __shared__ float M[HEADS * CAH * CH];
    if (t < C) {
        sq[t] = 1.f / fmaxf(sqrtf(ssq[b * C + t]), 1e-12f);
        sk[t] = 1.f / fmaxf(sqrtf(ssk[b * C + t]), 1e-12f);
    }
    if (t < CA) sa[t] = 1.f / fmaxf(sqrtf(ssa[b * CA + t]), 1e-12f);
    __syncthreads();
    if (t < HEADS * CH) {
        int h = t / CH, c = t % CH;
        const float* src = attn_a + ((size_t)(b * HEADS + h) * CH + c) * CAH;
        float ta = temp_a[h];
        float row[CAH];
        float mx = -1e30f;
#pragma unroll
        for (int d = 0; d < CAH; ++d) {
            row[d] = src[d] * sq[h * CH + c] * sa[h * CAH + d] * ta;
            mx = fmaxf(mx, row[d]);
        }
        float s = 0;
#pragma unroll
        for (int d = 0; d < CAH; ++d) { row[d] = __expf(row[d] - mx); s += row[d]; }
        float inv = 1.f / s;
#pragma unroll
        for (int d = 0; d < CAH; ++d) P[(h * CH + c) * CAH + d] = row[d] * inv;
    }
    if (t < HEADS * CAH) {
        int h = t / CAH, d = t % CAH;
        const float* src = attn_k + ((size_t)(b * HEADS + h) * CAH + d) * CH;
        float tv = temp_v[h];
        float row[CH];
        float mx = -1e30f;
#pragma unroll
        for (int c = 0; c < CH; ++c) {
            row[c] = src[c] * sa[h * CAH + d] * sk[h * CH + c] * tv;
            mx = fmaxf(mx, row[c]);
        }
        float s = 0;
#pragma unroll
        for (int c = 0; c < CH; ++c) { row[c] = __expf(row[c] - mx); s += row[c]; }
        float inv = 1.f / s;
#pragma unroll
        for (int c = 0; c < CH; ++c) M[(h * CAH + d) * CH + c] = row[c] * inv;
    }
    __syncthreads();
    for (int i = t; i < HEADS * CH * CH; i += 256) {
        int h = i / (CH * CH);
        int rr = i % (CH * CH);
        int c = rr / CH, c2 = rr % CH;
        float s = 0;
#pragma unroll
        for (int d = 0; d < CAH; ++d) s += P[(h * CH + c) * CAH + d] * M[(h * CAH + d) * CH + c2];
        Wout[(size_t)b * HEADS * CH * CH + i] = s;
    }
}

// ---------------- K5b: U[b][co][ci] = sum_c wo[co][h*24+c] * W[h][c][c'] ----------------
__global__ __launch_bounds__(256) void k_buildU(const float* Wout, const float* wo, short* U_b) {
    int bid = blockIdx.x;
    int b = bid / 12;
    int co0 = (bid % 12) * 16;
    int t = threadIdx.x;
    __shared__ float Wl[HEADS * CH * CH];
    for (int i = t; i < HEADS * CH * CH; i += 256) Wl[i] = Wout[(size_t)b * HEADS * CH * CH + i];
    __syncthreads();
    for (int u = t; u < 16 * C; u += 256) {
        int col = u / C;
        int ci = u % C;
        int co = co0 + col;
        int h = ci / CH, c2 = ci % CH;
        float s = 0;
#pragma unroll
        for (int c = 0; c < CH; ++c) s += wo[(size_t)co * C + h * CH + c] * Wl[(h * CH + c) * CH + c2];
        U_b[((size_t)b * C + co) * C + ci] = f2bf(s);
    }
}

// ---------------- K67: out = U @ (illu * (wv @ x)) -- two chained MFMA GEMMs ----------------
__global__ __launch_bounds__(256) void k_vout(const short* xT, const short* wv_b, const short* U_b,
                                              const float* illu, float* out) {
    int bid = blockIdx.x;
    int b = bid >> 10;
    int n0 = (bid & 1023) << 6;
    int tid = threadIdx.x;
    int lane = tid & 63;
    int wid = tid >> 6;
    int wm = wid & 1, wn = wid >> 1;
    int l15 = lane & 15, q = lane >> 4;
    __shared__ __align__(16) char lds_raw[C * 68 * 4];   // 52224B, reused
    short* ldsT = (short*)lds_raw;                       // [64][200] bf16
    float* ldsO = (float*)lds_raw;                       // [192][68] f32

    // GEMM1: vpre[co][px] = wv @ x
    f32x4 acc1[6][2] = {};
    {
        const short* bb = xT + ((size_t)b * HWN + n0 + wn * 32 + l15) * C + q * 8;
        const short* ab = wv_b + (size_t)(wm * 96 + l15) * C + q * 8;
#pragma unroll
        for (int ks = 0; ks < 6; ++ks) {
            bf16x8 bf0 = *(const bf16x8*)(bb + ks * 32);
            bf16x8 bf1 = *(const bf16x8*)(bb + (size_t)16 * C + ks * 32);
#pragma unroll
            for (int mt = 0; mt < 6; ++mt) {
                bf16x8 af = *(const bf16x8*)(ab + (size_t)mt * 16 * C + ks * 32);
                acc1[mt][0] = __builtin_amdgcn_mfma_f32_16x16x32_bf16(af, bf0, acc1[mt][0], 0, 0, 0);
                acc1[mt][1] = __builtin_amdgcn_mfma_f32_16x16x32_bf16(af, bf1, acc1[mt][1], 0, 0, 0);
            }
        }
    }
    // illu multiply, bf16, write ldsT[px][co]
    const float* ilb = illu + (size_t)b * C * HWN + n0;
#pragma unroll
    for (int mt = 0; mt < 6; ++mt)
#pragma unroll
        for (int nt = 0; nt < 2; ++nt) {
            int px = wn * 32 + nt * 16 + l15;
            short4v sv;
#pragma unroll
            for (int r = 0; r < 4; ++r) {
                int co = wm * 96 + mt * 16 + q * 4 + r;
                float il = ilb[(size_t)co * HWN + px];
                sv[r] = f2bf(acc1[mt][nt][r] * il);
            }
            *(short4v*)(&ldsT[px * 200 + wm * 96 + mt * 16 + q * 4]) = sv;
        }
    __syncthreads();
    // GEMM2: out[co][px] = U @ v   (B from LDS)
    f32x4 acc2[6][2] = {};
    {
        const short* ub = U_b + ((size_t)b * C + wm * 96 + l15) * C + q * 8;
        const short* tb = ldsT + (wn * 32 + l15) * 200 + q * 8;
#pragma unroll
        for (int ks = 0; ks < 6; ++ks) {
            bf16x8 bf0 = *(const bf16x8*)(tb + ks * 32);
            bf16x8 bf1 = *(const bf16x8*)(tb + 16 * 200 + ks * 32);
#pragma unroll
            for (int mt = 0; mt < 6; ++mt) {
                bf16x8 af = *(const bf16x8*)(ub + (size_t)mt * 16 * C + ks * 32);
                acc2[mt][0] = __builtin_amdgcn_mfma_f32_16x16x32_bf16(af, bf0, acc2[mt][0], 0, 0, 0);
                acc2[mt][1] = __builtin_amdgcn_mfma_f32_16x16x32_bf16(af, bf1, acc2[mt][1], 0, 0, 0);
            }
        }
    }
    __syncthreads();   // all LDS reads done before overwrite
#pragma unroll
    for (int mt = 0; mt < 6; ++mt)
#pragma unroll
        for (int nt = 0; nt < 2; ++nt) {
            int px = wn * 32 + nt * 16 + l15;
#pragma unroll
            for (int r = 0; r < 4; ++r) {
                int co = wm * 96 + mt * 16 + q * 4 + r;
                ldsO[co * 68 + px] = acc2[mt][nt][r];
            }
        }
    __syncthreads();
    float* ob = out + (size_t)b * C * HWN + n0;
    for (int it = 0; it < 12; ++it) {
        int u = tid + it * 256;        // 0..3071 = 192*16
        int co = u >> 4;
        int ch = u & 15;
        float4 vv = *(const float4*)(&ldsO[co * 68 + ch * 4]);
        *(float4*)(ob + (size_t)co * HWN + ch * 4) = vv;
    }
}

extern "C" void kernel_launch(void* const* d_in, const int* in_sizes, int n_in,
                              void* d_out, int out_size, void* d_ws, size_t ws_size,
                              hipStream_t stream) {
    (void)in_sizes; (void)n_in; (void)out_size;
    const float* x      = (const float*)d_in[0];
    const float* illu   = (const float*)d_in[1];
    const float* wq     = (const float*)d_in[2];
    const float* wk     = (const float*)d_in[3];
    const float* wa_dw  = (const float*)d_in[4];
    const float* wa_pw  = (const float*)d_in[5];
    const float* ba_pw  = (const float*)d_in[6];
    const float* wv     = (const float*)d_in[7];
    const float* wo     = (const float*)d_in[8];
    const float* temp_a = (const float*)d_in[9];
    const float* temp_v = (const float*)d_in[10];
    float* out = (float*)d_out;

    char* ws = (char*)d_ws;
    size_t off = 0;
    auto alloc = [&](size_t bytes) -> void* {
        void* p = ws + off;
        off += (bytes + 255) & ~(size_t)255;
        return p;
    };
    short* xT     = (short*)alloc((size_t)B * HWN * C * 2);   // 100.7 MB
    short* kbuf   = (short*)alloc((size_t)B * C * HW2 * 2);   // 25.2 MB
    short* qbuf   = (short*)alloc((size_t)B * C * HW2 * 2);   // 25.2 MB
    short* adwT   = (short*)alloc((size_t)B * HW2 * C * 2);   // 25.2 MB
    short* abuf   = (short*)alloc((size_t)B * CA * HW2 * 2);  // 12.6 MB
    short* wk_t   = (short*)alloc((size_t)9 * C * C * 2);
    short* wv_b   = (short*)alloc((size_t)C * C * 2);
    short* wapw_b = (short*)alloc((size_t)CA * C * 2);
    short* U_b    = (short*)alloc((size_t)B * C * C * 2);
    float* W_ws   = (float*)alloc((size_t)B * HEADS * CH * CH * 4);
    size_t accum_floats = (size_t)2 * B * C + B * CA + (size_t)2 * B * HEADS * CH * CAH;
    float* accum  = (float*)alloc(accum_floats * 4);
    float* ssq = accum;
    float* ssk = ssq + B * C;
    float* ssa = ssk + B * C;
    float* attn_a = ssa + B * CA;
    float* attn_k = attn_a + B * HEADS * CH * CAH;
    (void)ws_size;

    hipMemsetAsync(accum, 0, accum_floats * 4, stream);
    k_pack<<<1512, 256, 0, stream>>>(wk, wv, wa_pw, wk_t, wv_b, wapw_b);
    k_transpose<<<B * 1024, 256, 0, stream>>>(x, xT);
    k_kconv<<<1024, 256, 0, stream>>>(xT, wk_t, kbuf);
    k_dw<<<B * 12 * 128, 256, 0, stream>>>(x, wq, wa_dw, qbuf, adwT);
    k_apw<<<512, 256, 0, stream>>>(adwT, wapw_b, ba_pw, abuf);
    k_attn<<<2048, 64, 0, stream>>>(qbuf, kbuf, abuf, attn_a, attn_k, ssq, ssk, ssa);
    k_soft<<<B, 256, 0, stream>>>(ssq, ssk, ssa, attn_a, attn_k, temp_a, temp_v, W_ws);
    k_buildU<<<B * 12, 256, 0, stream>>>(W_ws, wo, U_b);
    k_vout<<<B * 1024, 256, 0, stream>>>(xT, wv_b, U_b, illu, out);
}

// Round 2
// 911.921 us; speedup vs baseline: 1.2786x; 1.0289x over previous
//
#include <hip/hip_runtime.h>
#include <stdint.h>

#define B 4
#define C 192
#define CA 96
#define HWN 65536
#define W2 128
#define HW2 16384
#define HEADS 8
#define CH 24
#define CAH 12

typedef short bf16x8 __attribute__((ext_vector_type(8)));
typedef short short4v __attribute__((ext_vector_type(4)));
typedef float f32x4 __attribute__((ext_vector_type(4)));
typedef unsigned int uint;

__device__ __forceinline__ float bf2f(short s) {
    union { uint u; float f; } v; v.u = ((uint)(unsigned short)s) << 16; return v.f;
}
__device__ __forceinline__ short f2bf(float f) {
    union { float f; uint u; } v; v.f = f;
    uint r = v.u + 0x7FFFu + ((v.u >> 16) & 1);
    return (short)(r >> 16);
}

// ---------------- K0: pack weights to bf16 ----------------
__global__ __launch_bounds__(256) void k_pack(const float* wk, const float* wv, const float* wapw,
                                              short* wk_t, short* wv_b, short* wapw_b) {
    int i = blockIdx.x * 256 + threadIdx.x;
    if (i < 331776) {                       // wk [co][ci][9] -> wk_t [tap][co][ci]
        int tap = i / 36864, r = i % 36864;
        int co = r / C, ci = r % C;
        wk_t[i] = f2bf(wk[(co * C + ci) * 9 + tap]);
    } else if (i < 331776 + 36864) {
        int j = i - 331776;
        wv_b[j] = f2bf(wv[j]);
    } else if (i < 331776 + 36864 + 18432) {
        int j = i - 368640;
        wapw_b[j] = f2bf(wapw[j]);
    }
}

// ---------------- K1: x [b][c][n] f32 -> xT [b][n][c] bf16 ----------------
__global__ __launch_bounds__(256) void k_transpose(const float* x, short* xT) {
    int bid = blockIdx.x;
    int b = bid >> 10;
    int n0 = (bid & 1023) << 6;
    __shared__ float tile[64][193];
    const float* xb = x + (size_t)b * C * HWN;
    int t = threadIdx.x;
    for (int it = 0; it < 12; ++it) {
        int i = t + it * 256;          // 0..3071
        int c = i >> 4;
        int j = i & 15;
        float4 v = *(const float4*)(xb + (size_t)c * HWN + n0 + j * 4);
        tile[j * 4 + 0][c] = v.x;
        tile[j * 4 + 1][c] = v.y;
        tile[j * 4 + 2][c] = v.z;
        tile[j * 4 + 3][c] = v.w;
    }
    __syncthreads();
    short* out = xT + ((size_t)b * HWN + n0) * C;
    for (int it = 0; it < 6; ++it) {
        int u = t + it * 256;          // 0..1535
        int n = u / 24;
        int cp = u % 24;
        int c0 = cp * 8;
        bf16x8 vv;
#pragma unroll
        for (int k2 = 0; k2 < 8; ++k2) vv[k2] = f2bf(tile[n][c0 + k2]);
        *(bf16x8*)(out + (size_t)n * C + c0) = vv;
    }
}

// ---------------- K2: k = conv3x3 s2 (192->192), m97-style: async LDS-staged B + reg-rotated A ----------------
// B-tile per tap staged k-granule-major: [24 g][64 px][16B] -> ds_read_b128 conflict-free,
// global_load_lds dest linear (tid*16), per-lane source does the im2col gather (+ zero stub at edges).
__global__ __launch_bounds__(256) void k_kconv(const short* xT, const short* wk_t, short* kout,
                                               const short* zbuf) {
    int orig = blockIdx.x;
    int bid = (orig & 7) * 128 + (orig >> 3);   // XCD swizzle: 1024 % 8 == 0, bijective
    int b = bid >> 8;
    int rem = bid & 255;
    int oh = rem >> 1;
    int owt = rem & 1;
    int tid = threadIdx.x;
    int lane = tid & 63;
    int wid = tid >> 6;
    int wm = wid & 1;          // co half (96)
    int wn = wid >> 1;         // px half (32)
    int l15 = lane & 15;
    int q = lane >> 4;

    __shared__ __align__(16) short lB[2][12288];   // 2 x 24KB double buffer

    const short* xTb = xT + (size_t)b * HWN * C;
    int px_s = tid & 63;
    int gb = tid >> 6;                 // granule base 0..3
    int ow_s = owt * 64 + px_s;

    auto stage = [&](int tap, int nb) {
        int kh = tap / 3, kw = tap % 3;
        int ih = 2 * oh - 1 + kh;
        int iw = 2 * ow_s - 1 + kw;
        bool v = ((unsigned)ih < 256u) && ((unsigned)iw < 256u);
        const short* src0 = v ? (xTb + ((size_t)ih * 256 + iw) * C) : zbuf;
        short* db = &lB[nb][0] + tid * 8;
#pragma unroll
        for (int s = 0; s < 6; ++s) {
            const short* sp = v ? (src0 + (gb + s * 4) * 8) : zbuf;
            __builtin_amdgcn_global_load_lds(
                (const __attribute__((address_space(1))) void*)sp,
                (__attribute__((address_space(3))) void*)(db + s * 2048), 16, 0, 0);
        }
    };

    f32x4 acc[6][2] = {};
    bf16x8 afc[6], afn[6];
    const short* ap = wk_t + (size_t)(wm * 96 + l15) * C + q * 8;

    stage(0, 0);
#pragma unroll
    for (int mt = 0; mt < 6; ++mt) afc[mt] = *(const bf16x8*)(ap + (size_t)mt * 16 * C);
    __syncthreads();

    for (int tap = 0; tap < 9; ++tap) {
        if (tap < 8) stage(tap + 1, (tap + 1) & 1);
        const short* lbB = &lB[tap & 1][0];
#pragma unroll
        for (int ks = 0; ks < 6; ++ks) {
            // prefetch A fragments for next (tap, ks)
            const short* apn = ap;
            int ksn = ks + 1;
            if (ks == 5) {
                ksn = (tap < 8) ? 0 : 5;
                apn = (tap < 8) ? (ap + C * C) : ap;
            }
#pragma unroll
            for (int mt = 0; mt < 6; ++mt)
                afn[mt] = *(const bf16x8*)(apn + (size_t)mt * 16 * C + ksn * 32);
            bf16x8 bf0 = *(const bf16x8*)(lbB + ((ks * 4 + q) * 64 + wn * 32 + l15) * 8);
            bf16x8 bf1 = *(const bf16x8*)(lbB + ((ks * 4 + q) * 64 + wn * 32 + 16 + l15) * 8);
#pragma unroll
            for (int mt = 0; mt < 6; ++mt) {
                acc[mt][0] = __builtin_amdgcn_mfma_f32_16x16x32_bf16(afc[mt], bf0, acc[mt][0], 0, 0, 0);
                acc[mt][1] = __builtin_amdgcn_mfma_f32_16x16x32_bf16(afc[mt], bf1, acc[mt][1], 0, 0, 0);
            }
#pragma unroll
            for (int mt = 0; mt < 6; ++mt) afc[mt] = afn[mt];
        }
        ap += C * C;
        __syncthreads();
    }

    // epilogue: stage to LDS (alias lB), convert, vector store
    short (*lt)[72] = (short (*)[72])(&lB[0][0]);   // 192*72*2 = 27648B <= 49152B
#pragma unroll
    for (int mt = 0; mt < 6; ++mt)
#pragma unroll
        for (int nt = 0; nt < 2; ++nt) {
            int px = wn * 32 + nt * 16 + l15;
#pragma unroll
            for (int r = 0; r < 4; ++r) {
                int co = wm * 96 + mt * 16 + q * 4 + r;
                lt[co][px] = f2bf(acc[mt][nt][r]);
            }
        }
    __syncthreads();
    short* kb = kout + (size_t)b * C * HW2 + oh * W2 + owt * 64;
    for (int it = 0; it < 6; ++it) {
        int u = tid + it * 256;      // 0..1535 = 192*8
        int co = u >> 3;
        int ch = u & 7;
        bf16x8 vv = *(const bf16x8*)(&lt[co][ch * 8]);
        *(bf16x8*)(kb + (size_t)co * HW2 + ch * 8) = vv;
    }
}

// ---------------- K2b: depthwise q (3x3 s2) + a_dw (3x3 s2) from planar f32 x ----------------
__global__ __launch_bounds__(256) void k_dw(const float* x, const float* wq, const float* wadw,
                                            short* qout, short* adwT) {
    int bid = blockIdx.x;
    int oh = bid & 127;
    int r2 = bid >> 7;              // b*12 + cg
    int cg = r2 % 12;
    int b  = r2 / 12;
    int t = threadIdx.x;
    int og = t & 15;                // ow group: ow0 = og*8
    int cl = t >> 4;                // 0..15 local channel
    int c = cg * 16 + cl;
    int ow0 = og * 8;

    float wq_r[9], wa_r[9];
#pragma unroll
    for (int k9 = 0; k9 < 9; ++k9) { wq_r[k9] = wq[c * 9 + k9]; wa_r[k9] = wadw[c * 9 + k9]; }

    const float* xp = x + (size_t)(b * C + c) * HWN;
    float qa[8] = {}, aa[8] = {};
    int ibase = 2 * ow0 - 4;
#pragma unroll
    for (int kh = 0; kh < 3; ++kh) {
        int ih = 2 * oh - 1 + kh;
        if ((unsigned)ih >= 256u) continue;     // zero pad (only oh==0, kh==0)
        const float* rp = xp + (size_t)ih * 256;
        float arr[20];
#pragma unroll
        for (int ck = 0; ck < 5; ++ck) {
            int iw = ibase + ck * 4;
            if (iw >= 0) {
                float4 v = *(const float4*)(rp + iw);
                arr[ck * 4 + 0] = v.x; arr[ck * 4 + 1] = v.y;
                arr[ck * 4 + 2] = v.z; arr[ck * 4 + 3] = v.w;
            } else {                             // left zero pad (og==0, chunk 0)
                arr[ck * 4 + 0] = 0.f; arr[ck * 4 + 1] = 0.f;
                arr[ck * 4 + 2] = 0.f; arr[ck * 4 + 3] = 0.f;
            }
        }
        float q0 = wq_r[kh * 3 + 0], q1 = wq_r[kh * 3 + 1], q2 = wq_r[kh * 3 + 2];
        float a0 = wa_r[kh * 3 + 0], a1 = wa_r[kh * 3 + 1], a2 = wa_r[kh * 3 + 2];
#pragma unroll
        for (int oz = 0; oz < 8; ++oz) {
            float s0 = arr[2 * oz + 3], s1 = arr[2 * oz + 4], s2 = arr[2 * oz + 5];
            qa[oz] += q0 * s0 + q1 * s1 + q2 * s2;
            aa[oz] += a0 * s0 + a1 * s1 + a2 * s2;
        }
    }

    // q out: [b][c][n2], one coalesced 16B store per thread
    bf16x8 qv;
#pragma unroll
    for (int oz = 0; oz < 8; ++oz) qv[oz] = f2bf(qa[oz]);
    *(bf16x8*)(qout + (size_t)(b * C + c) * HW2 + oh * W2 + ow0) = qv;

    // adw out: [b][n2][c] — stage tile [128 ow][16 c] (pad 17) then 16B stores
    __shared__ short la[128][17];
#pragma unroll
    for (int oz = 0; oz < 8; ++oz) la[ow0 + oz][cl] = f2bf(aa[oz]);
    __syncthreads();
    {
        int ow = t >> 1;
        int jh = (t & 1) * 8;
        bf16x8 vv;
#pragma unroll
        for (int j = 0; j < 8; ++j) vv[j] = la[ow][jh + j];
        short* dst = adwT + ((size_t)b * HW2 + (size_t)oh * W2 + ow) * C + cg * 16 + jh;
        *(bf16x8*)dst = vv;
    }
}

// ---------------- K2c: a = pointwise(adwT) + bias, MFMA ----------------
__global__ __launch_bounds__(256) void k_apw(const short* adwT, const short* wapw_b, const float* bapw,
                                             short* aout) {
    int bid = blockIdx.x;
    int b = bid >> 7;
    int op0 = (bid & 127) << 7;
    int tid = threadIdx.x;
    int lane = tid & 63;
    int wid = tid >> 6;
    int wm = wid & 1, wn = wid >> 1;
    int l15 = lane & 15, q = lane >> 4;
    f32x4 acc[3][4] = {};
    const short* bb = adwT + ((size_t)b * HW2 + op0 + wn * 64 + l15) * C + q * 8;
    const short* ab0 = wapw_b + (size_t)(wm * 48 + l15) * C + q * 8;
#pragma unroll
    for (int ks = 0; ks < 6; ++ks) {
        bf16x8 bf[4];
#pragma unroll
        for (int nt = 0; nt < 4; ++nt)
            bf[nt] = *(const bf16x8*)(bb + (size_t)nt * 16 * C + ks * 32);
#pragma unroll
        for (int mt = 0; mt < 3; ++mt) {
            bf16x8 af = *(const bf16x8*)(ab0 + (size_t)mt * 16 * C + ks * 32);
#pragma unroll
            for (int nt = 0; nt < 4; ++nt)
                acc[mt][nt] = __builtin_amdgcn_mfma_f32_16x16x32_bf16(af, bf[nt], acc[mt][nt], 0, 0, 0);
        }
    }
    __shared__ short la[CA][136];
#pragma unroll
    for (int mt = 0; mt < 3; ++mt)
#pragma unroll
        for (int nt = 0; nt < 4; ++nt) {
            int px = wn * 64 + nt * 16 + l15;
#pragma unroll
            for (int r = 0; r < 4; ++r) {
                int d = wm * 48 + mt * 16 + q * 4 + r;
                la[d][px] = f2bf(acc[mt][nt][r] + bapw[d]);
            }
        }
    __syncthreads();
    short* abp = aout + (size_t)b * CA * HW2 + op0;
    for (int it = 0; it < 6; ++it) {
        int u = tid + it * 256;       // 0..1535 = 96*16
        int d = u >> 4;
        int ch = u & 15;
        bf16x8 vv = *(const bf16x8*)(&la[d][ch * 8]);
        *(bf16x8*)(abp + (size_t)d * HW2 + ch * 8) = vv;
    }
}

// ---------------- K4: raw attention dots (MFMA over n) + sum-of-squares, atomic partials ----------------
__global__ __launch_bounds__(64) void k_attn(const short* qb, const short* kb, const short* abuf,
                                             float* attn_a, float* attn_k,
                                             float* ssq, float* ssk, float* ssa) {
    int bid = blockIdx.x;
    int b = bid >> 9;
    int rem = bid & 511;
    int h = rem >> 6;
    int cid = rem & 63;
    int lane = threadIdx.x;
    int l15 = lane & 15, q = lane >> 4;
    int n_base = cid * 256 + q * 8;
    int c1 = min(16 + l15, 23);
    int da = min(l15, 11);
    const short* qrow0 = qb + ((size_t)(b * C + h * CH + l15)) * HW2 + n_base;
    const short* qrow1 = qb + ((size_t)(b * C + h * CH + c1)) * HW2 + n_base;
    const short* krow0 = kb + ((size_t)(b * C + h * CH + l15)) * HW2 + n_base;
    const short* krow1 = kb + ((size_t)(b * C + h * CH + c1)) * HW2 + n_base;
    const short* arow = abuf + ((size_t)(b * CA + h * CAH + da)) * HW2 + n_base;
    f32x4 aa[2] = {};
    f32x4 ak[2] = {};
    float sq0 = 0, sq1 = 0, sk0 = 0, sk1 = 0, sa0 = 0;
#pragma unroll
    for (int ks = 0; ks < 8; ++ks) {
        bf16x8 qf0 = *(const bf16x8*)(qrow0 + ks * 32);
        bf16x8 qf1 = *(const bf16x8*)(qrow1 + ks * 32);
        bf16x8 kf0 = *(const bf16x8*)(krow0 + ks * 32);
        bf16x8 kf1 = *(const bf16x8*)(krow1 + ks * 32);
        bf16x8 af = *(const bf16x8*)(arow + ks * 32);
        aa[0] = __builtin_amdgcn_mfma_f32_16x16x32_bf16(qf0, af, aa[0], 0, 0, 0);
        aa[1] = __builtin_amdgcn_mfma_f32_16x16x32_bf16(qf1, af, aa[1], 0, 0, 0);
        ak[0] = __builtin_amdgcn_mfma_f32_16x16x32_bf16(af, kf0, ak[0], 0, 0, 0);
        ak[1] = __builtin_amdgcn_mfma_f32_16x16x32_bf16(af, kf1, ak[1], 0, 0, 0);
#pragma unroll
        for (int j = 0; j < 8; ++j) {
            float f;
            f = bf2f(qf0[j]); sq0 += f * f;
            f = bf2f(qf1[j]); sq1 += f * f;
            f = bf2f(kf0[j]); sk0 += f * f;
            f = bf2f(kf1[j]); sk1 += f * f;
            f = bf2f(af[j]);  sa0 += f * f;
        }
    }
    sq0 += __shfl_xor(sq0, 16); sq0 += __shfl_xor(sq0, 32);
    sq1 += __shfl_xor(sq1, 16); sq1 += __shfl_xor(sq1, 32);
    sk0 += __shfl_xor(sk0, 16); sk0 += __shfl_xor(sk0, 32);
    sk1 += __shfl_xor(sk1, 16); sk1 += __shfl_xor(sk1, 32);
    sa0 += __shfl_xor(sa0, 16); sa0 += __shfl_xor(sa0, 32);
    if (lane < 16) atomicAdd(&ssq[b * C + h * CH + lane], sq0);
    if (lane < 8)  atomicAdd(&ssq[b * C + h * CH + 16 + lane], sq1);
    if (lane < 16) atomicAdd(&ssk[b * C + h * CH + lane], sk0);
    if (lane < 8)  atomicAdd(&ssk[b * C + h * CH + 16 + lane], sk1);
    if (lane < 12) atomicAdd(&ssa[b * CA + h * CAH + lane], sa0);

    float* pa = attn_a + (size_t)(b * HEADS + h) * CH * CAH;
#pragma unroll
    for (int mt = 0; mt < 2; ++mt)
#pragma unroll
        for (int r = 0; r < 4; ++r) {
            int cc = mt * 16 + q * 4 + r;
            if (cc < 24 && l15 < 12) atomicAdd(&pa[cc * CAH + l15], aa[mt][r]);
        }
    float* pk = attn_k + (size_t)(b * HEADS + h) * CAH * CH;
#pragma unroll
    for (int nt = 0; nt < 2; ++nt)
#pragma unroll
        for (int r = 0; r < 4; ++r) {
            int dd = q * 4 + r;
            int cc = nt * 16 + l15;
            if (dd < 12 && cc < 24) atomicAdd(&pk[dd * CH + cc], ak[nt][r]);
        }
}

// ---------------- K5a: scales + softmax + W = P@M ----------------
__global__ __launch_bounds__(256) void k_soft(const float* ssq, const float* ssk, const float* ssa,
                                              const float* attn_a, const float* attn_k,
                                              const float* temp_a, const float* temp_v, float* Wout) {
    int b = blockIdx.x;
    int t = threadIdx.x;
    __shared__ float sq[C], sk[C], sa[CA];
    __shared__ float P[HEADS * CH * CAH];
    __shared__ float M[HEADS * CAH * CH];
    if (t < C) {
        sq[t] = 1.f / fmaxf(sqrtf(ssq[b * C + t]), 1e-12f);
        sk[t] = 1.f / fmaxf(sqrtf(ssk[b * C + t]), 1e-12f);
    }
    if (t < CA) sa[t] = 1.f / fmaxf(sqrtf(ssa[b * CA + t]), 1e-12f);
    __syncthreads();
    if (t < HEADS * CH) {
        int h = t / CH, c = t % CH;
        const float* src = attn_a + ((size_t)(b * HEADS + h) * CH + c) * CAH;
        float ta = temp_a[h];
        float row[CAH];
        float mx = -1e30f;
#pragma unroll
        for (int d = 0; d < CAH; ++d) {
            row[d] = src[d] * sq[h * CH + c] * sa[h * CAH + d] * ta;
            mx = fmaxf(mx, row[d]);
        }
        float s = 0;
#pragma unroll
        for (int d = 0; d < CAH; ++d) { row[d] = __expf(row[d] - mx); s += row[d]; }
        float inv = 1.f / s;
#pragma unroll
        for (int d = 0; d < CAH; ++d) P[(h * CH + c) * CAH + d] = row[d] * inv;
    }
    if (t < HEADS * CAH) {
        int h = t / CAH, d = t % CAH;
        const float* src = attn_k + ((size_t)(b * HEADS + h) * CAH + d) * CH;
        float tv = temp_v[h];
        float row[CH];
        float mx = -1e30f;
#pragma unroll
        for (int c = 0; c < CH; ++c) {
            row[c] = src[c] * sa[h * CAH + d] * sk[h * CH + c] * tv;
            mx = fmaxf(mx, row[c]);
        }
        float s = 0;
#pragma unroll
        for (int c = 0; c < CH; ++c) { row[c] = __expf(row[c] - mx); s += row[c]; }
        float inv = 1.f / s;
#pragma unroll
        for (int c = 0; c < CH; ++c) M[(h * CAH + d) * CH + c] = row[c] * inv;
    }
    __syncthreads();
    for (int i = t; i < HEADS * CH * CH; i += 256) {
        int h = i / (CH * CH);
        int rr = i % (CH * CH);
        int c = rr / CH, c2 = rr % CH;
        float s = 0;
#pragma unroll
        for (int d = 0; d < CAH; ++d) s += P[(h * CH + c) * CAH + d] * M[(h * CAH + d) * CH + c2];
        Wout[(size_t)b * HEADS * CH * CH + i] = s;
    }
}

// ---------------- K5b: U[b][co][ci] = sum_c wo[co][h*24+c] * W[h][c][c'] ----------------
__global__ __launch_bounds__(256) void k_buildU(const float* Wout, const float* wo, short* U_b) {
    int bid = blockIdx.x;
    int b = bid / 12;
    int co0 = (bid % 12) * 16;
    int t = threadIdx.x;
    __shared__ float Wl[HEADS * CH * CH];
    for (int i = t; i < HEADS * CH * CH; i += 256) Wl[i] = Wout[(size_t)b * HEADS * CH * CH + i];
    __syncthreads();
    for (int u = t; u < 16 * C; u += 256) {
        int col = u / C;
        int ci = u % C;
        int co = co0 + col;
        int h = ci / CH, c2 = ci % CH;
        float s = 0;
#pragma unroll
        for (int c = 0; c < CH; ++c) s += wo[(size_t)co * C + h * CH + c] * Wl[(h * CH + c) * CH + c2];
        U_b[((size_t)b * C + co) * C + ci] = f2bf(s);
    }
}

// ---------------- K67: out = U @ (illu * (wv @ x)) -- two chained MFMA GEMMs ----------------
__global__ __launch_bounds__(256) void k_vout(const short* xT, const short* wv_b, const short* U_b,
                                              const float* illu, float* out) {
    int bid = blockIdx.x;
    int b = bid >> 10;
    int n0 = (bid & 1023) << 6;
    int tid = threadIdx.x;
    int lane = tid & 63;
    int wid = tid >> 6;
    int wm = wid & 1, wn = wid >> 1;
    int l15 = lane & 15, q = lane >> 4;
    __shared__ __align__(16) char lds_raw[C * 68 * 4];   // 52224B, reused
    short* ldsT = (short*)lds_raw;                       // [64][200] bf16
    float* ldsO = (float*)lds_raw;                       // [192][68] f32

    // GEMM1: vpre[co][px] = wv @ x
    f32x4 acc1[6][2] = {};
    {
        const short* bb = xT + ((size_t)b * HWN + n0 + wn * 32 + l15) * C + q * 8;
        const short* ab = wv_b + (size_t)(wm * 96 + l15) * C + q * 8;
#pragma unroll
        for (int ks = 0; ks < 6; ++ks) {
            bf16x8 bf0 = *(const bf16x8*)(bb + ks * 32);
            bf16x8 bf1 = *(const bf16x8*)(bb + (size_t)16 * C + ks * 32);
#pragma unroll
            for (int mt = 0; mt < 6; ++mt) {
                bf16x8 af = *(const bf16x8*)(ab + (size_t)mt * 16 * C + ks * 32);
                acc1[mt][0] = __builtin_amdgcn_mfma_f32_16x16x32_bf16(af, bf0, acc1[mt][0], 0, 0, 0);
                acc1[mt][1] = __builtin_amdgcn_mfma_f32_16x16x32_bf16(af, bf1, acc1[mt][1], 0, 0, 0);
            }
        }
    }
    // illu multiply, bf16, write ldsT[px][co]
    const float* ilb = illu + (size_t)b * C * HWN + n0;
#pragma unroll
    for (int mt = 0; mt < 6; ++mt)
#pragma unroll
        for (int nt = 0; nt < 2; ++nt) {
            int px = wn * 32 + nt * 16 + l15;
            short4v sv;
#pragma unroll
            for (int r = 0; r < 4; ++r) {
                int co = wm * 96 + mt * 16 + q * 4 + r;
                float il = ilb[(size_t)co * HWN + px];
                sv[r] = f2bf(acc1[mt][nt][r] * il);
            }
            *(short4v*)(&ldsT[px * 200 + wm * 96 + mt * 16 + q * 4]) = sv;
        }
    __syncthreads();
    // GEMM2: out[co][px] = U @ v   (B from LDS)
    f32x4 acc2[6][2] = {};
    {
        const short* ub = U_b + ((size_t)b * C + wm * 96 + l15) * C + q * 8;
        const short* tb = ldsT + (wn * 32 + l15) * 200 + q * 8;
#pragma unroll
        for (int ks = 0; ks < 6; ++ks) {
            bf16x8 bf0 = *(const bf16x8*)(tb + ks * 32);
            bf16x8 bf1 = *(const bf16x8*)(tb + 16 * 200 + ks * 32);
#pragma unroll
            for (int mt = 0; mt < 6; ++mt) {
                bf16x8 af = *(const bf16x8*)(ub + (size_t)mt * 16 * C + ks * 32);
                acc2[mt][0] = __builtin_amdgcn_mfma_f32_16x16x32_bf16(af, bf0, acc2[mt][0], 0, 0, 0);
                acc2[mt][1] = __builtin_amdgcn_mfma_f32_16x16x32_bf16(af, bf1, acc2[mt][1], 0, 0, 0);
            }
        }
    }
    __syncthreads();   // all LDS reads done before overwrite
#pragma unroll
    for (int mt = 0; mt < 6; ++mt)
#pragma unroll
        for (int nt = 0; nt < 2; ++nt) {
            int px = wn * 32 + nt * 16 + l15;
#pragma unroll
            for (int r = 0; r < 4; ++r) {
                int co = wm * 96 + mt * 16 + q * 4 + r;
                ldsO[co * 68 + px] = acc2[mt][nt][r];
            }
        }
    __syncthreads();
    float* ob = out + (size_t)b * C * HWN + n0;
    for (int it = 0; it < 12; ++it) {
        int u = tid + it * 256;        // 0..3071 = 192*16
        int co = u >> 4;
        int ch = u & 15;
        float4 vv = *(const float4*)(&ldsO[co * 68 + ch * 4]);
        *(float4*)(ob + (size_t)co * HWN + ch * 4) = vv;
    }
}

extern "C" void kernel_launch(void* const* d_in, const int* in_sizes, int n_in,
                              void* d_out, int out_size, void* d_ws, size_t ws_size,
                              hipStream_t stream) {
    (void)in_sizes; (void)n_in; (void)out_size;
    const float* x      = (const float*)d_in[0];
    const float* illu   = (const float*)d_in[1];
    const float* wq     = (const float*)d_in[2];
    const float* wk     = (const float*)d_in[3];
    const float* wa_dw  = (const float*)d_in[4];
    const float* wa_pw  = (const float*)d_in[5];
    const float* ba_pw  = (const float*)d_in[6];
    const float* wv     = (const float*)d_in[7];
    const float* wo     = (const float*)d_in[8];
    const float* temp_a = (const float*)d_in[9];
    const float* temp_v = (const float*)d_in[10];
    float* out = (float*)d_out;

    char* ws = (char*)d_ws;
    size_t off = 0;
    auto alloc = [&](size_t bytes) -> void* {
        void* p = ws + off;
        off += (bytes + 255) & ~(size_t)255;
        return p;
    };
    short* xT     = (short*)alloc((size_t)B * HWN * C * 2);   // 100.7 MB
    short* kbuf   = (short*)alloc((size_t)B * C * HW2 * 2);   // 25.2 MB
    short* qbuf   = (short*)alloc((size_t)B * C * HW2 * 2);   // 25.2 MB
    short* adwT   = (short*)alloc((size_t)B * HW2 * C * 2);   // 25.2 MB
    short* abuf   = (short*)alloc((size_t)B * CA * HW2 * 2);  // 12.6 MB
    short* wk_t   = (short*)alloc((size_t)9 * C * C * 2);
    short* wv_b   = (short*)alloc((size_t)C * C * 2);
    short* wapw_b = (short*)alloc((size_t)CA * C * 2);
    short* U_b    = (short*)alloc((size_t)B * C * C * 2);
    float* W_ws   = (float*)alloc((size_t)B * HEADS * CH * CH * 4);
    short* zbuf   = (short*)alloc(256);
    size_t accum_floats = (size_t)2 * B * C + B * CA + (size_t)2 * B * HEADS * CH * CAH;
    float* accum  = (float*)alloc(accum_floats * 4);
    float* ssq = accum;
    float* ssk = ssq + B * C;
    float* ssa = ssk + B * C;
    float* attn_a = ssa + B * CA;
    float* attn_k = attn_a + B * HEADS * CH * CAH;
    (void)ws_size;

    hipMemsetAsync(accum, 0, accum_floats * 4, stream);
    hipMemsetAsync(zbuf, 0, 256, stream);
    k_pack<<<1512, 256, 0, stream>>>(wk, wv, wa_pw, wk_t, wv_b, wapw_b);
    k_transpose<<<B * 1024, 256, 0, stream>>>(x, xT);
    k_kconv<<<1024, 256, 0, stream>>>(xT, wk_t, kbuf, zbuf);
    k_dw<<<B * 12 * 128, 256, 0, stream>>>(x, wq, wa_dw, qbuf, adwT);
    k_apw<<<512, 256, 0, stream>>>(adwT, wapw_b, ba_pw, abuf);
    k_attn<<<2048, 64, 0, stream>>>(qbuf, kbuf, abuf, attn_a, attn_k, ssq, ssk, ssa);
    k_soft<<<B, 256, 0, stream>>>(ssq, ssk, ssa, attn_a, attn_k, temp_a, temp_v, W_ws);
    k_buildU<<<B * 12, 256, 0, stream>>>(W_ws, wo, U_b);
    k_vout<<<B * 1024, 256, 0, stream>>>(xT, wv_b, U_b, illu, out);
}